// Round 1
// baseline (450.057 us; speedup 1.0000x reference)
//
#include <hip/hip_runtime.h>
#include <hip/hip_bf16.h>

typedef __bf16 bf16_t;
typedef __attribute__((ext_vector_type(4))) __bf16 bf16x4;
typedef __attribute__((ext_vector_type(8))) __bf16 bf16x8;
typedef __attribute__((ext_vector_type(4))) float f32x4;

#define MFMA16(a, b, c) __builtin_amdgcn_mfma_f32_16x16x32_bf16((a), (b), (c), 0, 0, 0)

// ---- constants ----
#define BB 16
#define SS 1024
#define DD 512
#define HH 8
#define DH 64
#define NTOK (BB * SS)          // 16384

typedef const __attribute__((address_space(1))) void gas_void;
typedef __attribute__((address_space(3))) void las_void;

__device__ __forceinline__ void async_cp16(const void* g, void* l) {
    __builtin_amdgcn_global_load_lds((gas_void*)g, (las_void*)l, 16, 0, 0);
}

// Load one MFMA A/B fragment (16x16x32 bf16) from a swizzled [rows][64] bf16 LDS
// tile (128 B/row, 16B chunk position = chunk ^ (row&7)).
// Element mapping: lane l, elem j -> k = 16*(j>>2) + 4*(l>>4) + (j&3).
__device__ __forceinline__ bf16x8 frag_ld(const char* sm, int row, int kk, int g) {
    int r7 = row & 7;
    int base = row * 128 + ((g & 1) << 3);
    int c0 = ((kk << 2) + (g >> 1)) ^ r7;
    int c1 = ((kk << 2) + 2 + (g >> 1)) ^ r7;
    bf16x4 lo = *(const bf16x4*)(sm + base + (c0 << 4));
    bf16x4 hi = *(const bf16x4*)(sm + base + (c1 << 4));
    return __builtin_shufflevector(lo, hi, 0, 1, 2, 3, 4, 5, 6, 7);
}

// ---------------- cast x -> bf16 ----------------
__global__ __launch_bounds__(256) void cast_x_k(const float* __restrict__ x,
                                                bf16_t* __restrict__ xb, int n4) {
    int i = blockIdx.x * 256 + threadIdx.x;
    if (i < n4) {
        float4 v = ((const float4*)x)[i];
        bf16x4 o;
        o[0] = (bf16_t)v.x; o[1] = (bf16_t)v.y; o[2] = (bf16_t)v.z; o[3] = (bf16_t)v.w;
        *(bf16x4*)(xb + (size_t)i * 4) = o;
    }
}

// ---------------- transpose + cast weights: Wt[n][k] = W[k][n] ----------------
__global__ __launch_bounds__(256) void transpose_w_k(const float* __restrict__ W0,
                                                     const float* __restrict__ W1,
                                                     const float* __restrict__ W2,
                                                     const float* __restrict__ W3,
                                                     bf16_t* __restrict__ Wt) {
    __shared__ float t[32][33];
    int z = blockIdx.z;
    const float* W = (z == 0) ? W0 : (z == 1) ? W1 : (z == 2) ? W2 : W3;
    bf16_t* out = Wt + (size_t)z * DD * DD;
    int n0 = blockIdx.x * 32, k0 = blockIdx.y * 32;
    int tx = threadIdx.x, ty = threadIdx.y;  // (32, 8)
#pragma unroll
    for (int i = 0; i < 32; i += 8)
        t[ty + i][tx] = W[(size_t)(k0 + ty + i) * DD + n0 + tx];
    __syncthreads();
#pragma unroll
    for (int i = 0; i < 32; i += 8)
        out[(size_t)(n0 + ty + i) * DD + k0 + tx] = (bf16_t)t[tx][ty + i];
}

// ---------------- GEMM: C[M,512] = A[M,512] * W (given W^T[n][k]) ----------------
// MODE 0: grid.z selects Q(0)/K(1)/V(2); Q,K stored [bh][s][dh] bf16, V stored
//         transposed [bh][dh][s] bf16.
// MODE 2: O projection, fp32 out + bias + query mask.
template <int MODE>
__global__ __launch_bounds__(256) void gemm_k(const bf16_t* __restrict__ A,
                                              const bf16_t* __restrict__ WtBase,
                                              bf16_t* __restrict__ oQ,
                                              bf16_t* __restrict__ oK,
                                              bf16_t* __restrict__ oVt,
                                              float* __restrict__ oO,
                                              const float* __restrict__ bo,
                                              const int* __restrict__ seq_lens) {
    __shared__ __align__(16) char smem[32768];
    char* smA = smem;
    char* smB = smem + 16384;
    const int tid = threadIdx.x;
    const int l = tid & 63, w = tid >> 6;
    const int lr = l & 15, g = l >> 4;
    const int bm = blockIdx.x, bn = blockIdx.y;
    const int z = (MODE == 0) ? blockIdx.z : 3;
    const bf16_t* Wt = WtBase + (size_t)z * DD * DD;
    const int row0 = bm * 128;
    const int col0 = bn * 128;
    const int wm = (w >> 1) * 64, wn = (w & 1) * 64;

    f32x4 acc[4][4] = {};

    for (int kt = 0; kt < 8; ++kt) {
        const int k0 = kt * 64;
        __syncthreads();
#pragma unroll
        for (int it = 0; it < 4; ++it) {
            int cl = it * 256 + tid;
            int m = cl >> 3, p = cl & 7, c = p ^ (m & 7);
            async_cp16(A + (size_t)(row0 + m) * DD + k0 + c * 8, smA + cl * 16);
        }
#pragma unroll
        for (int it = 0; it < 4; ++it) {
            int cl = it * 256 + tid;
            int m = cl >> 3, p = cl & 7, c = p ^ (m & 7);
            async_cp16(Wt + (size_t)(col0 + m) * DD + k0 + c * 8, smB + cl * 16);
        }
        __syncthreads();
#pragma unroll
        for (int kk = 0; kk < 2; ++kk) {
            bf16x8 af[4], bfr[4];
#pragma unroll
            for (int i = 0; i < 4; ++i) af[i] = frag_ld(smA, wm + i * 16 + lr, kk, g);
#pragma unroll
            for (int j = 0; j < 4; ++j) bfr[j] = frag_ld(smB, wn + j * 16 + lr, kk, g);
#pragma unroll
            for (int i = 0; i < 4; ++i)
#pragma unroll
                for (int j = 0; j < 4; ++j)
                    acc[i][j] = MFMA16(af[i], bfr[j], acc[i][j]);
        }
    }

    if (MODE == 0) {
        if (z < 2) {
            bf16_t* outp = (z == 0) ? oQ : oK;
#pragma unroll
            for (int i = 0; i < 4; ++i) {
                int mrow = row0 + wm + i * 16 + g * 4;
#pragma unroll
                for (int j = 0; j < 4; ++j) {
                    int n = col0 + wn + j * 16 + lr;
                    int h = n >> 6, dh = n & 63;
#pragma unroll
                    for (int r = 0; r < 4; ++r) {
                        int m = mrow + r;
                        int b = m >> 10, s = m & 1023;
                        outp[((size_t)((b * HH + h) * SS + s)) * DH + dh] =
                            (bf16_t)acc[i][j][r];
                    }
                }
            }
        } else {
            // V: transpose to [bh][dh][s] via LDS
            __syncthreads();
            bf16_t* tsm = (bf16_t*)smem;
#pragma unroll
            for (int i = 0; i < 4; ++i)
#pragma unroll
                for (int j = 0; j < 4; ++j)
#pragma unroll
                    for (int r = 0; r < 4; ++r)
                        tsm[(wm + i * 16 + g * 4 + r) * 128 + wn + j * 16 + lr] =
                            (bf16_t)acc[i][j][r];
            __syncthreads();
            int nloc = tid >> 1;
            int mbase = (tid & 1) * 64;
            int n = col0 + nloc;
            int h = n >> 6, dh = n & 63;
            int b = row0 >> 10;  // 128-row block spans a single batch
            int s0 = (row0 & 1023) + mbase;
            bf16_t* dst = oVt + ((size_t)((b * HH + h) * DH + dh)) * SS + s0;
#pragma unroll
            for (int mm = 0; mm < 64; mm += 8) {
                bf16x8 v;
#pragma unroll
                for (int e = 0; e < 8; ++e) v[e] = tsm[(mbase + mm + e) * 128 + nloc];
                *(bf16x8*)(dst + mm) = v;
            }
        }
    } else {
        int b = row0 >> 10;
        int len = seq_lens[b];
#pragma unroll
        for (int i = 0; i < 4; ++i) {
            int mrow = row0 + wm + i * 16 + g * 4;
#pragma unroll
            for (int j = 0; j < 4; ++j) {
                int n = col0 + wn + j * 16 + lr;
                float bias = bo[n];
#pragma unroll
                for (int r = 0; r < 4; ++r) {
                    int m = mrow + r;
                    int s = m & 1023;
                    oO[(size_t)m * DD + n] = (s < len) ? (acc[i][j][r] + bias) : 0.f;
                }
            }
        }
    }
}

// ---------------- fused flash attention ----------------
// block: 4 waves, one (bh, 64-q-row tile); wave w owns q rows [q0+16w, q0+16w+16)
__global__ __launch_bounds__(256) void attn_k(const bf16_t* __restrict__ Q,
                                              const bf16_t* __restrict__ K,
                                              const bf16_t* __restrict__ Vt,
                                              bf16_t* __restrict__ O,
                                              const int* __restrict__ seq_lens) {
    __shared__ __align__(16) char psm[8192];  // per-wave 2KB P buffer (swizzled)
    const int tid = threadIdx.x, l = tid & 63, w = tid >> 6;
    const int bh = blockIdx.x & 127, qt = blockIdx.x >> 7;
    const int b = bh >> 3, h = bh & 7;
    const int len = seq_lens[b];
    const int q0 = qt * 64;
    if (q0 >= len) return;  // fully padded q tile: output masked later anyway
    const int lr = l & 15, g = l >> 4;

    const int qrow = q0 + w * 16 + lr;
    const bf16_t* qp = Q + ((size_t)bh * SS + qrow) * DH;
    bf16x8 aq[2];
#pragma unroll
    for (int kk = 0; kk < 2; ++kk) {
        bf16x4 lo = *(const bf16x4*)(qp + kk * 32 + 4 * g);
        bf16x4 hi = *(const bf16x4*)(qp + kk * 32 + 16 + 4 * g);
        aq[kk] = __builtin_shufflevector(lo, hi, 0, 1, 2, 3, 4, 5, 6, 7);
    }

    f32x4 oacc[4] = {};
    float mrun[4], lrun[4];
#pragma unroll
    for (int r = 0; r < 4; ++r) { mrun[r] = -1e30f; lrun[r] = 0.f; }

    char* myp = psm + w * 2048;
    const int nkt = (len + 63) >> 6;
    const bf16_t* kbase = K + (size_t)bh * SS * DH;
    const bf16_t* vbase = Vt + (size_t)bh * DH * SS;

    for (int kt = 0; kt < nkt; ++kt) {
        const int key0 = kt * 64;
        f32x4 sc[4];
#pragma unroll
        for (int nt = 0; nt < 4; ++nt) {
            const bf16_t* kp = kbase + (size_t)(key0 + nt * 16 + lr) * DH;
            f32x4 zz = {};
#pragma unroll
            for (int kk = 0; kk < 2; ++kk) {
                bf16x4 lo = *(const bf16x4*)(kp + kk * 32 + 4 * g);
                bf16x4 hi = *(const bf16x4*)(kp + kk * 32 + 16 + 4 * g);
                bf16x8 bk = __builtin_shufflevector(lo, hi, 0, 1, 2, 3, 4, 5, 6, 7);
                zz = MFMA16(aq[kk], bk, zz);
            }
            sc[nt] = zz;
        }
        // scale + key mask
#pragma unroll
        for (int nt = 0; nt < 4; ++nt) {
            bool valid = (key0 + nt * 16 + lr) < len;
#pragma unroll
            for (int r = 0; r < 4; ++r) {
                float s = sc[nt][r] * 0.125f;
                sc[nt][r] = valid ? s : -1e30f;
            }
        }
        // row max (across 16 lanes of the l&15 group)
        float vm[4];
#pragma unroll
        for (int r = 0; r < 4; ++r)
            vm[r] = fmaxf(fmaxf(sc[0][r], sc[1][r]), fmaxf(sc[2][r], sc[3][r]));
#pragma unroll
        for (int r = 0; r < 4; ++r) {
#pragma unroll
            for (int off = 1; off < 16; off <<= 1)
                vm[r] = fmaxf(vm[r], __shfl_xor(vm[r], off, 64));
        }
        float corr[4];
#pragma unroll
        for (int r = 0; r < 4; ++r) {
            float mn = fmaxf(mrun[r], vm[r]);
            corr[r] = __expf(mrun[r] - mn);
            mrun[r] = mn;
        }
        // p = exp(s - m): LDS (swizzled) + row sums
        float vs[4] = {0.f, 0.f, 0.f, 0.f};
#pragma unroll
        for (int nt = 0; nt < 4; ++nt) {
#pragma unroll
            for (int r = 0; r < 4; ++r) {
                float p = __expf(sc[nt][r] - mrun[r]);
                vs[r] += p;
                int q = g * 4 + r;
                int keyl = nt * 16 + lr;
                int byte = q * 128 + (((keyl >> 3) ^ (q & 7)) << 4) + ((keyl & 7) << 1);
                *(bf16_t*)(myp + byte) = (bf16_t)p;
            }
        }
#pragma unroll
        for (int r = 0; r < 4; ++r) {
#pragma unroll
            for (int off = 1; off < 16; off <<= 1)
                vs[r] += __shfl_xor(vs[r], off, 64);
            lrun[r] = lrun[r] * corr[r] + vs[r];
        }
#pragma unroll
        for (int dt = 0; dt < 4; ++dt)
#pragma unroll
            for (int r = 0; r < 4; ++r) oacc[dt][r] *= corr[r];
        // PV
#pragma unroll
        for (int kk = 0; kk < 2; ++kk) {
            bf16x8 ap = frag_ld(myp, lr, kk, g);
#pragma unroll
            for (int dt = 0; dt < 4; ++dt) {
                const bf16_t* vp = vbase + (size_t)(dt * 16 + lr) * SS + key0 + kk * 32;
                bf16x4 vlo = *(const bf16x4*)(vp + 4 * g);
                bf16x4 vhi = *(const bf16x4*)(vp + 16 + 4 * g);
                bf16x8 bv = __builtin_shufflevector(vlo, vhi, 0, 1, 2, 3, 4, 5, 6, 7);
                oacc[dt] = MFMA16(ap, bv, oacc[dt]);
            }
        }
    }
    // epilogue: normalize + store [token][h*64+dh] bf16
#pragma unroll
    for (int r = 0; r < 4; ++r) {
        float inv = 1.f / lrun[r];
        int q = q0 + w * 16 + g * 4 + r;
        size_t orow = ((size_t)b * SS + q) * DD;
#pragma unroll
        for (int dt = 0; dt < 4; ++dt)
            O[orow + h * DH + dt * 16 + lr] = (bf16_t)(oacc[dt][r] * inv);
    }
}

extern "C" void kernel_launch(void* const* d_in, const int* in_sizes, int n_in,
                              void* d_out, int out_size, void* d_ws, size_t ws_size,
                              hipStream_t stream) {
    const float* x = (const float*)d_in[0];
    const int* seq_lens = (const int*)d_in[1];
    const float* Wq = (const float*)d_in[2];
    const float* Wk = (const float*)d_in[3];
    const float* Wv = (const float*)d_in[4];
    const float* Wo = (const float*)d_in[5];
    const float* bo = (const float*)d_in[6];
    float* out = (float*)d_out;

    char* ws = (char*)d_ws;
    const size_t SEG = (size_t)NTOK * DD * sizeof(bf16_t);  // 16 MB
    bf16_t* xb = (bf16_t*)ws;          // also reused as attention output 'ab'
    bf16_t* qb = (bf16_t*)(ws + SEG);
    bf16_t* kb = (bf16_t*)(ws + 2 * SEG);
    bf16_t* vtb = (bf16_t*)(ws + 3 * SEG);
    bf16_t* wt = (bf16_t*)(ws + 4 * SEG);
    bf16_t* ab = xb;

    cast_x_k<<<dim3((NTOK * DD / 4) / 256), dim3(256), 0, stream>>>(x, xb, NTOK * DD / 4);
    transpose_w_k<<<dim3(16, 16, 4), dim3(32, 8), 0, stream>>>(Wq, Wk, Wv, Wo, wt);
    gemm_k<0><<<dim3(NTOK / 128, DD / 128, 3), dim3(256), 0, stream>>>(
        xb, wt, qb, kb, vtb, nullptr, nullptr, nullptr);
    attn_k<<<dim3(BB * HH * (SS / 64)), dim3(256), 0, stream>>>(qb, kb, vtb, ab, seq_lens);
    gemm_k<2><<<dim3(NTOK / 128, DD / 128, 1), dim3(256), 0, stream>>>(
        ab, wt, nullptr, nullptr, nullptr, out, bo, seq_lens);
}

// Round 2
// 132.140 us; speedup vs baseline: 3.4059x; 3.4059x over previous
//
#include <hip/hip_runtime.h>
#include <hip/hip_bf16.h>

typedef __bf16 bf16_t;
typedef __attribute__((ext_vector_type(4))) __bf16 bf16x4;
typedef __attribute__((ext_vector_type(8))) __bf16 bf16x8;
typedef __attribute__((ext_vector_type(4))) float f32x4;

#define MFMA16(a, b, c) __builtin_amdgcn_mfma_f32_16x16x32_bf16((a), (b), (c), 0, 0, 0)

// ---- constants ----
#define BB 16
#define SS 1024
#define DD 512
#define HH 8
#define DH 64
#define NTOK (BB * SS)          // 16384

typedef const __attribute__((address_space(1))) void gas_void;
typedef __attribute__((address_space(3))) void las_void;

__device__ __forceinline__ void async_cp16(const void* g, void* l) {
    __builtin_amdgcn_global_load_lds((gas_void*)g, (las_void*)l, 16, 0, 0);
}

// Load one MFMA A/B fragment (16x16x32 bf16) from a swizzled [rows][64] bf16 LDS
// tile (128 B/row, 16B chunk position = chunk ^ (row&7)).
// Element mapping: lane l, elem j -> k = 16*(j>>2) + 4*(l>>4) + (j&3).
__device__ __forceinline__ bf16x8 frag_ld(const char* sm, int row, int kk, int g) {
    int r7 = row & 7;
    int base = row * 128 + ((g & 1) << 3);
    int c0 = ((kk << 2) + (g >> 1)) ^ r7;
    int c1 = ((kk << 2) + 2 + (g >> 1)) ^ r7;
    bf16x4 lo = *(const bf16x4*)(sm + base + (c0 << 4));
    bf16x4 hi = *(const bf16x4*)(sm + base + (c1 << 4));
    return __builtin_shufflevector(lo, hi, 0, 1, 2, 3, 4, 5, 6, 7);
}

// ---------------- cast x -> bf16 ----------------
__global__ __launch_bounds__(256) void cast_x_k(const float* __restrict__ x,
                                                bf16_t* __restrict__ xb, int n4) {
    int i = blockIdx.x * 256 + threadIdx.x;
    if (i < n4) {
        float4 v = ((const float4*)x)[i];
        bf16x4 o;
        o[0] = (bf16_t)v.x; o[1] = (bf16_t)v.y; o[2] = (bf16_t)v.z; o[3] = (bf16_t)v.w;
        *(bf16x4*)(xb + (size_t)i * 4) = o;
    }
}

// ---------------- transpose + cast weights: Wt[n][k] = W[k][n] ----------------
__global__ __launch_bounds__(256) void transpose_w_k(const float* __restrict__ W0,
                                                     const float* __restrict__ W1,
                                                     const float* __restrict__ W2,
                                                     const float* __restrict__ W3,
                                                     bf16_t* __restrict__ Wt) {
    __shared__ float t[32][33];
    int z = blockIdx.z;
    const float* W = (z == 0) ? W0 : (z == 1) ? W1 : (z == 2) ? W2 : W3;
    bf16_t* out = Wt + (size_t)z * DD * DD;
    int n0 = blockIdx.x * 32, k0 = blockIdx.y * 32;
    int tx = threadIdx.x, ty = threadIdx.y;  // (32, 8)
#pragma unroll
    for (int i = 0; i < 32; i += 8)
        t[ty + i][tx] = W[(size_t)(k0 + ty + i) * DD + n0 + tx];
    __syncthreads();
#pragma unroll
    for (int i = 0; i < 32; i += 8)
        out[(size_t)(n0 + ty + i) * DD + k0 + tx] = (bf16_t)t[tx][ty + i];
}

// ---------------- GEMM: C[M,512] = A[M,512] * W (given W^T[n][k]) ----------------
// MODE 0: grid.z selects Q(0)/K(1)/V(2); Q,K stored [bh][s][dh] bf16, V stored
//         transposed [bh][dh][s] bf16.
// MODE 2: O projection, fp32 out + bias + query mask.
template <int MODE>
__global__ __launch_bounds__(256) void gemm_k(const bf16_t* __restrict__ A,
                                              const bf16_t* __restrict__ WtBase,
                                              bf16_t* __restrict__ oQ,
                                              bf16_t* __restrict__ oK,
                                              bf16_t* __restrict__ oVt,
                                              float* __restrict__ oO,
                                              const float* __restrict__ bo,
                                              const int* __restrict__ seq_lens) {
    __shared__ __align__(16) char smem[32768];
    char* smA = smem;
    char* smB = smem + 16384;
    const int tid = threadIdx.x;
    const int l = tid & 63, w = tid >> 6;
    const int lr = l & 15, g = l >> 4;
    const int bm = blockIdx.x, bn = blockIdx.y;
    const int z = (MODE == 0) ? blockIdx.z : 3;
    const bf16_t* Wt = WtBase + (size_t)z * DD * DD;
    const int row0 = bm * 128;
    const int col0 = bn * 128;
    const int wm = (w >> 1) * 64, wn = (w & 1) * 64;

    f32x4 acc[4][4] = {};

    for (int kt = 0; kt < 8; ++kt) {
        const int k0 = kt * 64;
        __syncthreads();
#pragma unroll
        for (int it = 0; it < 4; ++it) {
            int cl = it * 256 + tid;
            int m = cl >> 3, p = cl & 7, c = p ^ (m & 7);
            async_cp16(A + (size_t)(row0 + m) * DD + k0 + c * 8, smA + cl * 16);
        }
#pragma unroll
        for (int it = 0; it < 4; ++it) {
            int cl = it * 256 + tid;
            int m = cl >> 3, p = cl & 7, c = p ^ (m & 7);
            async_cp16(Wt + (size_t)(col0 + m) * DD + k0 + c * 8, smB + cl * 16);
        }
        __syncthreads();
#pragma unroll
        for (int kk = 0; kk < 2; ++kk) {
            bf16x8 af[4], bfr[4];
#pragma unroll
            for (int i = 0; i < 4; ++i) af[i] = frag_ld(smA, wm + i * 16 + lr, kk, g);
#pragma unroll
            for (int j = 0; j < 4; ++j) bfr[j] = frag_ld(smB, wn + j * 16 + lr, kk, g);
#pragma unroll
            for (int i = 0; i < 4; ++i)
#pragma unroll
                for (int j = 0; j < 4; ++j)
                    acc[i][j] = MFMA16(af[i], bfr[j], acc[i][j]);
        }
    }

    if (MODE == 0) {
        if (z < 2) {
            bf16_t* outp = (z == 0) ? oQ : oK;
#pragma unroll
            for (int i = 0; i < 4; ++i) {
                int mrow = row0 + wm + i * 16 + g * 4;
#pragma unroll
                for (int j = 0; j < 4; ++j) {
                    int n = col0 + wn + j * 16 + lr;
                    int h = n >> 6, dh = n & 63;
#pragma unroll
                    for (int r = 0; r < 4; ++r) {
                        int m = mrow + r;
                        int b = m >> 10, s = m & 1023;
                        outp[((size_t)((b * HH + h) * SS + s)) * DH + dh] =
                            (bf16_t)acc[i][j][r];
                    }
                }
            }
        } else {
            // V: transpose to [bh][dh][s] via LDS
            __syncthreads();
            bf16_t* tsm = (bf16_t*)smem;
#pragma unroll
            for (int i = 0; i < 4; ++i)
#pragma unroll
                for (int j = 0; j < 4; ++j)
#pragma unroll
                    for (int r = 0; r < 4; ++r)
                        tsm[(wm + i * 16 + g * 4 + r) * 128 + wn + j * 16 + lr] =
                            (bf16_t)acc[i][j][r];
            __syncthreads();
            int nloc = tid >> 1;
            int mbase = (tid & 1) * 64;
            int n = col0 + nloc;
            int h = n >> 6, dh = n & 63;
            int b = row0 >> 10;  // 128-row block spans a single batch
            int s0 = (row0 & 1023) + mbase;
            bf16_t* dst = oVt + ((size_t)((b * HH + h) * DH + dh)) * SS + s0;
#pragma unroll
            for (int mm = 0; mm < 64; mm += 8) {
                bf16x8 v;
#pragma unroll
                for (int e = 0; e < 8; ++e) v[e] = tsm[(mbase + mm + e) * 128 + nloc];
                *(bf16x8*)(dst + mm) = v;
            }
        }
    } else {
        int b = row0 >> 10;
        int len = seq_lens[b];
#pragma unroll
        for (int i = 0; i < 4; ++i) {
            int mrow = row0 + wm + i * 16 + g * 4;
#pragma unroll
            for (int j = 0; j < 4; ++j) {
                int n = col0 + wn + j * 16 + lr;
                float bias = bo[n];
#pragma unroll
                for (int r = 0; r < 4; ++r) {
                    int m = mrow + r;
                    int s = m & 1023;
                    oO[(size_t)m * DD + n] = (s < len) ? (acc[i][j][r] + bias) : 0.f;
                }
            }
        }
    }
}

// ---------------- fused flash attention (swapped QK^T, LDS-staged K/V) --------
// block: 4 waves, 128 q-rows (wave w owns q0+w*32 .. +32, 2 subtiles of 16).
// Per kt (KVBLK=64): P^T = mfma(K_frag, Q_frag) -> lane holds P[q=lr][k=4g+r+16nt]
// which IS the PV A-fragment layout (k = 16*(j>>2)+4g+(j&3)) -> no P movement.
__global__ __launch_bounds__(256) void attn_k(const bf16_t* __restrict__ Q,
                                              const bf16_t* __restrict__ K,
                                              const bf16_t* __restrict__ Vt,
                                              bf16_t* __restrict__ O,
                                              const int* __restrict__ seq_lens) {
    __shared__ __align__(16) char smem[32768];  // 2 bufs x (K 8KB + V 8KB)
    const int tid = threadIdx.x, l = tid & 63, w = tid >> 6;
    const int bh = blockIdx.x & 127, qt = blockIdx.x >> 7;
    const int b = bh >> 3, h = bh & 7;
    const int len = seq_lens[b];
    const int q0 = qt * 128;
    if (q0 >= len) return;  // fully padded q tile: masked in final GEMM
    const int lr = l & 15, g = l >> 4;

    const bf16_t* kbase = K + (size_t)bh * SS * DH;
    const bf16_t* vbase = Vt + (size_t)bh * DH * SS;

    // Q fragments (B-operand: lane holds col q=lr, rows d = 16*(j>>2)+4g+(j&3))
    bf16x8 bq[2][2];
#pragma unroll
    for (int qs = 0; qs < 2; ++qs) {
        const bf16_t* qp = Q + ((size_t)bh * SS + q0 + w * 32 + qs * 16 + lr) * DH;
#pragma unroll
        for (int kk = 0; kk < 2; ++kk) {
            bf16x4 lo = *(const bf16x4*)(qp + kk * 32 + 4 * g);
            bf16x4 hi = *(const bf16x4*)(qp + kk * 32 + 16 + 4 * g);
            bq[qs][kk] = __builtin_shufflevector(lo, hi, 0, 1, 2, 3, 4, 5, 6, 7);
        }
    }

    f32x4 oacc[2][4] = {};                 // [qsub][dt] ; rows q=4g+r, col dh=lr
    float mrun[2] = {-1e30f, -1e30f};      // lr-layout (q = qs*16 + lr)
    float lpart[2] = {0.f, 0.f};           // per-lane partial sum (own 4g+r slice)

    const int nkt = (len + 63) >> 6;

    // stage K[key0..key0+64)[64dh] and Vt[64dh][key0..key0+64) into buf (swizzled)
    auto stage = [&](int buf, int key0) {
        char* smK = smem + buf * 16384;
        char* smV = smK + 8192;
#pragma unroll
        for (int it = 0; it < 2; ++it) {
            int cl = it * 256 + tid;
            int m = cl >> 3, p = cl & 7, c = p ^ (m & 7);
            async_cp16(kbase + (size_t)(key0 + m) * DH + c * 8, smK + cl * 16);
        }
#pragma unroll
        for (int it = 0; it < 2; ++it) {
            int cl = it * 256 + tid;
            int m = cl >> 3, p = cl & 7, c = p ^ (m & 7);
            async_cp16(vbase + (size_t)m * SS + key0 + c * 8, smV + cl * 16);
        }
    };

    stage(0, 0);
    __syncthreads();

    for (int kt = 0; kt < nkt; ++kt) {
        const int key0 = kt * 64;
        const char* smK = smem + (kt & 1) * 16384;
        const char* smV = smK + 8192;
        if (kt + 1 < nkt) stage((kt + 1) & 1, key0 + 64);

        // QK^T (swapped): pacc[qs][nt] = P^T tile rows k=nt*16+4g+r, col q=lr
        f32x4 pacc[2][4] = {};
#pragma unroll
        for (int nt = 0; nt < 4; ++nt) {
            bf16x8 ak0 = frag_ld(smK, nt * 16 + lr, 0, g);
            bf16x8 ak1 = frag_ld(smK, nt * 16 + lr, 1, g);
#pragma unroll
            for (int qs = 0; qs < 2; ++qs) {
                pacc[qs][nt] = MFMA16(ak0, bq[qs][0], pacc[qs][nt]);
                pacc[qs][nt] = MFMA16(ak1, bq[qs][1], pacc[qs][nt]);
            }
        }

#pragma unroll
        for (int qs = 0; qs < 2; ++qs) {
            // scale + key mask + local max
            float mloc = -1e30f;
#pragma unroll
            for (int nt = 0; nt < 4; ++nt)
#pragma unroll
                for (int r = 0; r < 4; ++r) {
                    int kg = key0 + nt * 16 + 4 * g + r;
                    float s = pacc[qs][nt][r] * 0.125f;
                    s = (kg < len) ? s : -1e30f;
                    pacc[qs][nt][r] = s;
                    mloc = fmaxf(mloc, s);
                }
            mloc = fmaxf(mloc, __shfl_xor(mloc, 16, 64));
            mloc = fmaxf(mloc, __shfl_xor(mloc, 32, 64));
            float mn = fmaxf(mrun[qs], mloc);
            float corr = __expf(mrun[qs] - mn);
            mrun[qs] = mn;
            // p = exp(s-m), local partial sum (cross-lane reduce deferred)
            float ls = 0.f;
#pragma unroll
            for (int nt = 0; nt < 4; ++nt)
#pragma unroll
                for (int r = 0; r < 4; ++r) {
                    float p = __expf(pacc[qs][nt][r] - mn);
                    pacc[qs][nt][r] = p;
                    ls += p;
                }
            lpart[qs] = lpart[qs] * corr + ls;
            // broadcast corr into O-layout (q = 4g+r) and rescale O
            float cb[4];
#pragma unroll
            for (int r = 0; r < 4; ++r) cb[r] = __shfl(corr, 4 * g + r, 64);
#pragma unroll
            for (int dt = 0; dt < 4; ++dt)
#pragma unroll
                for (int r = 0; r < 4; ++r) oacc[qs][dt][r] *= cb[r];
            // pack P to bf16 A-fragments (already in A-layout)
            bf16x8 pa[2];
#pragma unroll
            for (int kf = 0; kf < 2; ++kf)
#pragma unroll
                for (int j = 0; j < 8; ++j)
                    pa[kf][j] = (bf16_t)pacc[qs][2 * kf + (j >> 2)][j & 3];
            // PV
#pragma unroll
            for (int kf = 0; kf < 2; ++kf)
#pragma unroll
                for (int dt = 0; dt < 4; ++dt) {
                    bf16x8 bv = frag_ld(smV, dt * 16 + lr, kf, g);
                    oacc[qs][dt] = MFMA16(pa[kf], bv, oacc[qs][dt]);
                }
        }
        __syncthreads();
    }

    // epilogue: finish l reduce, normalize, store [token][h*64+dh]
#pragma unroll
    for (int qs = 0; qs < 2; ++qs) {
        float lt = lpart[qs];
        lt += __shfl_xor(lt, 16, 64);
        lt += __shfl_xor(lt, 32, 64);
#pragma unroll
        for (int r = 0; r < 4; ++r) {
            float inv = 1.f / __shfl(lt, 4 * g + r, 64);
            int q = q0 + w * 32 + qs * 16 + 4 * g + r;
            size_t orow = ((size_t)b * SS + q) * DD;
#pragma unroll
            for (int dt = 0; dt < 4; ++dt)
                O[orow + h * DH + dt * 16 + lr] = (bf16_t)(oacc[qs][dt][r] * inv);
        }
    }
}

extern "C" void kernel_launch(void* const* d_in, const int* in_sizes, int n_in,
                              void* d_out, int out_size, void* d_ws, size_t ws_size,
                              hipStream_t stream) {
    const float* x = (const float*)d_in[0];
    const int* seq_lens = (const int*)d_in[1];
    const float* Wq = (const float*)d_in[2];
    const float* Wk = (const float*)d_in[3];
    const float* Wv = (const float*)d_in[4];
    const float* Wo = (const float*)d_in[5];
    const float* bo = (const float*)d_in[6];
    float* out = (float*)d_out;

    char* ws = (char*)d_ws;
    const size_t SEG = (size_t)NTOK * DD * sizeof(bf16_t);  // 16 MB
    bf16_t* xb = (bf16_t*)ws;          // also reused as attention output 'ab'
    bf16_t* qb = (bf16_t*)(ws + SEG);
    bf16_t* kb = (bf16_t*)(ws + 2 * SEG);
    bf16_t* vtb = (bf16_t*)(ws + 3 * SEG);
    bf16_t* wt = (bf16_t*)(ws + 4 * SEG);
    bf16_t* ab = xb;

    cast_x_k<<<dim3((NTOK * DD / 4) / 256), dim3(256), 0, stream>>>(x, xb, NTOK * DD / 4);
    transpose_w_k<<<dim3(16, 16, 4), dim3(32, 8), 0, stream>>>(Wq, Wk, Wv, Wo, wt);
    gemm_k<0><<<dim3(NTOK / 128, DD / 128, 3), dim3(256), 0, stream>>>(
        xb, wt, qb, kb, vtb, nullptr, nullptr, nullptr);
    attn_k<<<dim3(BB * HH * (SS / 128)), dim3(256), 0, stream>>>(qb, kb, vtb, ab, seq_lens);
    gemm_k<2><<<dim3(NTOK / 128, DD / 128, 1), dim3(256), 0, stream>>>(
        ab, wt, nullptr, nullptr, nullptr, out, bo, seq_lens);
}

// Round 3
// 129.780 us; speedup vs baseline: 3.4679x; 1.0182x over previous
//
#include <hip/hip_runtime.h>
#include <hip/hip_bf16.h>

typedef __bf16 bf16_t;
typedef __attribute__((ext_vector_type(4))) __bf16 bf16x4;
typedef __attribute__((ext_vector_type(8))) __bf16 bf16x8;
typedef __attribute__((ext_vector_type(4))) float f32x4;

#define MFMA16(a, b, c) __builtin_amdgcn_mfma_f32_16x16x32_bf16((a), (b), (c), 0, 0, 0)

// ---- constants ----
#define BB 16
#define SS 1024
#define DD 512
#define HH 8
#define DH 64
#define NTOK (BB * SS)          // 16384
#define QSCALE 0.18033688f      // dh^-0.5 * log2(e) folded into Q projection

typedef const __attribute__((address_space(1))) void gas_void;
typedef __attribute__((address_space(3))) void las_void;

__device__ __forceinline__ void async_cp16(const void* g, void* l) {
    __builtin_amdgcn_global_load_lds((gas_void*)g, (las_void*)l, 16, 0, 0);
}

// Load one MFMA A/B fragment (16x16x32 bf16) from a swizzled [rows][64] bf16 LDS
// tile (128 B/row, 16B chunk position = chunk ^ (row&7)).
// Element mapping: lane l, elem j -> k = 16*(j>>2) + 4*(l>>4) + (j&3).
__device__ __forceinline__ bf16x8 frag_ld(const char* sm, int row, int kk, int g) {
    int r7 = row & 7;
    int base = row * 128 + ((g & 1) << 3);
    int c0 = ((kk << 2) + (g >> 1)) ^ r7;
    int c1 = ((kk << 2) + 2 + (g >> 1)) ^ r7;
    bf16x4 lo = *(const bf16x4*)(sm + base + (c0 << 4));
    bf16x4 hi = *(const bf16x4*)(sm + base + (c1 << 4));
    return __builtin_shufflevector(lo, hi, 0, 1, 2, 3, 4, 5, 6, 7);
}

// ---------------- cast x -> bf16 ----------------
__global__ __launch_bounds__(256) void cast_x_k(const float* __restrict__ x,
                                                bf16_t* __restrict__ xb, int n4) {
    int i = blockIdx.x * 256 + threadIdx.x;
    if (i < n4) {
        float4 v = ((const float4*)x)[i];
        bf16x4 o;
        o[0] = (bf16_t)v.x; o[1] = (bf16_t)v.y; o[2] = (bf16_t)v.z; o[3] = (bf16_t)v.w;
        *(bf16x4*)(xb + (size_t)i * 4) = o;
    }
}

// ---------------- transpose + cast weights: Wt[n][k] = W[k][n] ----------------
__global__ __launch_bounds__(256) void transpose_w_k(const float* __restrict__ W0,
                                                     const float* __restrict__ W1,
                                                     const float* __restrict__ W2,
                                                     const float* __restrict__ W3,
                                                     bf16_t* __restrict__ Wt) {
    __shared__ float t[32][33];
    int z = blockIdx.z;
    const float* W = (z == 0) ? W0 : (z == 1) ? W1 : (z == 2) ? W2 : W3;
    bf16_t* out = Wt + (size_t)z * DD * DD;
    int n0 = blockIdx.x * 32, k0 = blockIdx.y * 32;
    int tx = threadIdx.x, ty = threadIdx.y;  // (32, 8)
#pragma unroll
    for (int i = 0; i < 32; i += 8)
        t[ty + i][tx] = W[(size_t)(k0 + ty + i) * DD + n0 + tx];
    __syncthreads();
#pragma unroll
    for (int i = 0; i < 32; i += 8)
        out[(size_t)(n0 + ty + i) * DD + k0 + tx] = (bf16_t)t[tx][ty + i];
}

// ---------------- GEMM: C[M,512] = A[M,512] * W (given W^T[n][k]) ----------------
// MODE 0: grid.z selects Q(0)/K(1)/V(2); Q,K stored [bh][s][dh] bf16 (Q scaled by
//         QSCALE), V stored transposed [bh][dh][s] bf16.
// MODE 2: O projection, fp32 out + bias + query mask.
template <int MODE>
__global__ __launch_bounds__(256) void gemm_k(const bf16_t* __restrict__ A,
                                              const bf16_t* __restrict__ WtBase,
                                              bf16_t* __restrict__ oQ,
                                              bf16_t* __restrict__ oK,
                                              bf16_t* __restrict__ oVt,
                                              float* __restrict__ oO,
                                              const float* __restrict__ bo,
                                              const int* __restrict__ seq_lens) {
    __shared__ __align__(16) char smem[32768];
    char* smA = smem;
    char* smB = smem + 16384;
    const int tid = threadIdx.x;
    const int l = tid & 63, w = tid >> 6;
    const int lr = l & 15, g = l >> 4;
    const int bm = blockIdx.x, bn = blockIdx.y;
    const int z = (MODE == 0) ? blockIdx.z : 3;
    const bf16_t* Wt = WtBase + (size_t)z * DD * DD;
    const int row0 = bm * 128;
    const int col0 = bn * 128;
    const int wm = (w >> 1) * 64, wn = (w & 1) * 64;

    f32x4 acc[4][4] = {};

    for (int kt = 0; kt < 8; ++kt) {
        const int k0 = kt * 64;
        __syncthreads();
#pragma unroll
        for (int it = 0; it < 4; ++it) {
            int cl = it * 256 + tid;
            int m = cl >> 3, p = cl & 7, c = p ^ (m & 7);
            async_cp16(A + (size_t)(row0 + m) * DD + k0 + c * 8, smA + cl * 16);
        }
#pragma unroll
        for (int it = 0; it < 4; ++it) {
            int cl = it * 256 + tid;
            int m = cl >> 3, p = cl & 7, c = p ^ (m & 7);
            async_cp16(Wt + (size_t)(col0 + m) * DD + k0 + c * 8, smB + cl * 16);
        }
        __syncthreads();
#pragma unroll
        for (int kk = 0; kk < 2; ++kk) {
            bf16x8 af[4], bfr[4];
#pragma unroll
            for (int i = 0; i < 4; ++i) af[i] = frag_ld(smA, wm + i * 16 + lr, kk, g);
#pragma unroll
            for (int j = 0; j < 4; ++j) bfr[j] = frag_ld(smB, wn + j * 16 + lr, kk, g);
#pragma unroll
            for (int i = 0; i < 4; ++i)
#pragma unroll
                for (int j = 0; j < 4; ++j)
                    acc[i][j] = MFMA16(af[i], bfr[j], acc[i][j]);
        }
    }

    if (MODE == 0) {
        if (z < 2) {
            bf16_t* outp = (z == 0) ? oQ : oK;
            const float sc = (z == 0) ? QSCALE : 1.f;
#pragma unroll
            for (int i = 0; i < 4; ++i) {
                int mrow = row0 + wm + i * 16 + g * 4;
#pragma unroll
                for (int j = 0; j < 4; ++j) {
                    int n = col0 + wn + j * 16 + lr;
                    int h = n >> 6, dh = n & 63;
#pragma unroll
                    for (int r = 0; r < 4; ++r) {
                        int m = mrow + r;
                        int b = m >> 10, s = m & 1023;
                        outp[((size_t)((b * HH + h) * SS + s)) * DH + dh] =
                            (bf16_t)(acc[i][j][r] * sc);
                    }
                }
            }
        } else {
            // V: transpose to [bh][dh][s] via LDS
            __syncthreads();
            bf16_t* tsm = (bf16_t*)smem;
#pragma unroll
            for (int i = 0; i < 4; ++i)
#pragma unroll
                for (int j = 0; j < 4; ++j)
#pragma unroll
                    for (int r = 0; r < 4; ++r)
                        tsm[(wm + i * 16 + g * 4 + r) * 128 + wn + j * 16 + lr] =
                            (bf16_t)acc[i][j][r];
            __syncthreads();
            int nloc = tid >> 1;
            int mbase = (tid & 1) * 64;
            int n = col0 + nloc;
            int h = n >> 6, dh = n & 63;
            int b = row0 >> 10;  // 128-row block spans a single batch
            int s0 = (row0 & 1023) + mbase;
            bf16_t* dst = oVt + ((size_t)((b * HH + h) * DH + dh)) * SS + s0;
#pragma unroll
            for (int mm = 0; mm < 64; mm += 8) {
                bf16x8 v;
#pragma unroll
                for (int e = 0; e < 8; ++e) v[e] = tsm[(mbase + mm + e) * 128 + nloc];
                *(bf16x8*)(dst + mm) = v;
            }
        }
    } else {
        int b = row0 >> 10;
        int len = seq_lens[b];
#pragma unroll
        for (int i = 0; i < 4; ++i) {
            int mrow = row0 + wm + i * 16 + g * 4;
#pragma unroll
            for (int j = 0; j < 4; ++j) {
                int n = col0 + wn + j * 16 + lr;
                float bias = bo[n];
#pragma unroll
                for (int r = 0; r < 4; ++r) {
                    int m = mrow + r;
                    int s = m & 1023;
                    oO[(size_t)m * DD + n] = (s < len) ? (acc[i][j][r] + bias) : 0.f;
                }
            }
        }
    }
}

// ---------------- fused flash attention (swapped QK^T, LDS-staged K/V) --------
// block: 4 waves, 128 q-rows. Scores arrive in log2-domain (Q pre-scaled), so
// p = v_exp_f32(t - m) directly. blockIdx remapped: XCD = bh&7 (K/V L2
// locality) while a CU's co-resident blocks span different batches (balance).
__global__ __launch_bounds__(256) void attn_k(const bf16_t* __restrict__ Q,
                                              const bf16_t* __restrict__ K,
                                              const bf16_t* __restrict__ Vt,
                                              bf16_t* __restrict__ O,
                                              const int* __restrict__ seq_lens) {
    __shared__ __align__(16) char smem[32768];  // 2 bufs x (K 8KB + V 8KB)
    const int tid = threadIdx.x, l = tid & 63, w = tid >> 6;
    const int o = blockIdx.x;
    const int bh = ((o >> 6) << 3) | (o & 7);   // b' = o>>6, x = o&7
    const int qt = (o >> 3) & 7;
    const int b = bh >> 3, h = bh & 7;
    const int len = seq_lens[b];
    const int q0 = qt * 128;
    if (q0 >= len) return;  // fully padded q tile: masked in final GEMM
    const int lr = l & 15, g = l >> 4;

    const bf16_t* kbase = K + (size_t)bh * SS * DH;
    const bf16_t* vbase = Vt + (size_t)bh * DH * SS;

    // Q fragments (B-operand: lane holds col q=lr, rows d = 16*(j>>2)+4g+(j&3))
    bf16x8 bq[2][2];
#pragma unroll
    for (int qs = 0; qs < 2; ++qs) {
        const bf16_t* qp = Q + ((size_t)bh * SS + q0 + w * 32 + qs * 16 + lr) * DH;
#pragma unroll
        for (int kk = 0; kk < 2; ++kk) {
            bf16x4 lo = *(const bf16x4*)(qp + kk * 32 + 4 * g);
            bf16x4 hi = *(const bf16x4*)(qp + kk * 32 + 16 + 4 * g);
            bq[qs][kk] = __builtin_shufflevector(lo, hi, 0, 1, 2, 3, 4, 5, 6, 7);
        }
    }

    f32x4 oacc[2][4] = {};                 // [qsub][dt] ; rows q=4g+r, col dh=lr
    float mrun[2] = {-1e30f, -1e30f};      // per-lane: q = qs*16 + lr
    float lpart[2] = {0.f, 0.f};           // per-lane partial sum (own 4g+r slice)

    const int nkt = (len + 63) >> 6;

    auto stage = [&](int buf, int key0) {
        char* smK = smem + buf * 16384;
        char* smV = smK + 8192;
#pragma unroll
        for (int it = 0; it < 2; ++it) {
            int cl = it * 256 + tid;
            int m = cl >> 3, p = cl & 7, c = p ^ (m & 7);
            async_cp16(kbase + (size_t)(key0 + m) * DH + c * 8, smK + cl * 16);
        }
#pragma unroll
        for (int it = 0; it < 2; ++it) {
            int cl = it * 256 + tid;
            int m = cl >> 3, p = cl & 7, c = p ^ (m & 7);
            async_cp16(vbase + (size_t)m * SS + key0 + c * 8, smV + cl * 16);
        }
    };

    stage(0, 0);
    __syncthreads();

    for (int kt = 0; kt < nkt; ++kt) {
        const int key0 = kt * 64;
        const char* smK = smem + (kt & 1) * 16384;
        const char* smV = smK + 8192;
        if (kt + 1 < nkt) stage((kt + 1) & 1, key0 + 64);

        // QK^T (swapped): pacc[qs][nt] = P^T tile rows k=nt*16+4g+r, col q=lr
        f32x4 pacc[2][4] = {};
#pragma unroll
        for (int nt = 0; nt < 4; ++nt) {
            bf16x8 ak0 = frag_ld(smK, nt * 16 + lr, 0, g);
            bf16x8 ak1 = frag_ld(smK, nt * 16 + lr, 1, g);
#pragma unroll
            for (int qs = 0; qs < 2; ++qs) {
                pacc[qs][nt] = MFMA16(ak0, bq[qs][0], pacc[qs][nt]);
                pacc[qs][nt] = MFMA16(ak1, bq[qs][1], pacc[qs][nt]);
            }
        }

        const bool full = (key0 + 64 <= len);  // wave-uniform

#pragma unroll
        for (int qs = 0; qs < 2; ++qs) {
            // (mask +) local max  — scores already log2-domain
            float mloc = -1e30f;
            if (full) {
#pragma unroll
                for (int nt = 0; nt < 4; ++nt)
#pragma unroll
                    for (int r = 0; r < 4; ++r) mloc = fmaxf(mloc, pacc[qs][nt][r]);
            } else {
#pragma unroll
                for (int nt = 0; nt < 4; ++nt)
#pragma unroll
                    for (int r = 0; r < 4; ++r) {
                        int kg = key0 + nt * 16 + 4 * g + r;
                        float s = (kg < len) ? pacc[qs][nt][r] : -1e30f;
                        pacc[qs][nt][r] = s;
                        mloc = fmaxf(mloc, s);
                    }
            }
            mloc = fmaxf(mloc, __shfl_xor(mloc, 16, 64));
            mloc = fmaxf(mloc, __shfl_xor(mloc, 32, 64));

            float mn;
            if (__all(mloc <= mrun[qs])) {
                // corr == 1 exactly: no rescale needed
                mn = mrun[qs];
            } else {
                mn = fmaxf(mrun[qs], mloc);
                float corr = __builtin_amdgcn_exp2f(mrun[qs] - mn);
                mrun[qs] = mn;
                lpart[qs] *= corr;
                float cb[4];
#pragma unroll
                for (int r = 0; r < 4; ++r) cb[r] = __shfl(corr, 4 * g + r, 64);
#pragma unroll
                for (int dt = 0; dt < 4; ++dt)
#pragma unroll
                    for (int r = 0; r < 4; ++r) oacc[qs][dt][r] *= cb[r];
            }

            // p = 2^(t - m), accumulate per-lane partial sum
            float ls = 0.f;
#pragma unroll
            for (int nt = 0; nt < 4; ++nt)
#pragma unroll
                for (int r = 0; r < 4; ++r) {
                    float p = __builtin_amdgcn_exp2f(pacc[qs][nt][r] - mn);
                    pacc[qs][nt][r] = p;
                    ls += p;
                }
            lpart[qs] += ls;

            // pack P to bf16 A-fragments (already in A-layout)
            bf16x8 pa[2];
#pragma unroll
            for (int kf = 0; kf < 2; ++kf)
#pragma unroll
                for (int j = 0; j < 8; ++j)
                    pa[kf][j] = (bf16_t)pacc[qs][2 * kf + (j >> 2)][j & 3];
            // PV
#pragma unroll
            for (int kf = 0; kf < 2; ++kf)
#pragma unroll
                for (int dt = 0; dt < 4; ++dt) {
                    bf16x8 bv = frag_ld(smV, dt * 16 + lr, kf, g);
                    oacc[qs][dt] = MFMA16(pa[kf], bv, oacc[qs][dt]);
                }
        }
        __syncthreads();
    }

    // epilogue: finish l reduce, normalize, store [token][h*64+dh]
#pragma unroll
    for (int qs = 0; qs < 2; ++qs) {
        float lt = lpart[qs];
        lt += __shfl_xor(lt, 16, 64);
        lt += __shfl_xor(lt, 32, 64);
#pragma unroll
        for (int r = 0; r < 4; ++r) {
            float inv = 1.f / __shfl(lt, 4 * g + r, 64);
            int q = q0 + w * 32 + qs * 16 + 4 * g + r;
            size_t orow = ((size_t)b * SS + q) * DD;
#pragma unroll
            for (int dt = 0; dt < 4; ++dt)
                O[orow + h * DH + dt * 16 + lr] = (bf16_t)(oacc[qs][dt][r] * inv);
        }
    }
}

extern "C" void kernel_launch(void* const* d_in, const int* in_sizes, int n_in,
                              void* d_out, int out_size, void* d_ws, size_t ws_size,
                              hipStream_t stream) {
    const float* x = (const float*)d_in[0];
    const int* seq_lens = (const int*)d_in[1];
    const float* Wq = (const float*)d_in[2];
    const float* Wk = (const float*)d_in[3];
    const float* Wv = (const float*)d_in[4];
    const float* Wo = (const float*)d_in[5];
    const float* bo = (const float*)d_in[6];
    float* out = (float*)d_out;

    char* ws = (char*)d_ws;
    const size_t SEG = (size_t)NTOK * DD * sizeof(bf16_t);  // 16 MB
    bf16_t* xb = (bf16_t*)ws;          // also reused as attention output 'ab'
    bf16_t* qb = (bf16_t*)(ws + SEG);
    bf16_t* kb = (bf16_t*)(ws + 2 * SEG);
    bf16_t* vtb = (bf16_t*)(ws + 3 * SEG);
    bf16_t* wt = (bf16_t*)(ws + 4 * SEG);
    bf16_t* ab = xb;

    cast_x_k<<<dim3((NTOK * DD / 4) / 256), dim3(256), 0, stream>>>(x, xb, NTOK * DD / 4);
    transpose_w_k<<<dim3(16, 16, 4), dim3(32, 8), 0, stream>>>(Wq, Wk, Wv, Wo, wt);
    gemm_k<0><<<dim3(NTOK / 128, DD / 128, 3), dim3(256), 0, stream>>>(
        xb, wt, qb, kb, vtb, nullptr, nullptr, nullptr);
    attn_k<<<dim3(BB * HH * (SS / 128)), dim3(256), 0, stream>>>(qb, kb, vtb, ab, seq_lens);
    gemm_k<2><<<dim3(NTOK / 128, DD / 128, 1), dim3(256), 0, stream>>>(
        ab, wt, nullptr, nullptr, nullptr, out, bo, seq_lens);
}